// Round 3
// baseline (8973.112 us; speedup 1.0000x reference)
//
#include <hip/hip_runtime.h>

#define TT 96
#define DM 64
#define DI 128
#define NSTATE 16
#define NN 325
#define NBATCH 16
#define CHT 16           // t-chunk size for phase A
#define NCH (TT / CHT)   // 6 chunks
#define WXLD 129         // wxT row stride: +1 pad, read as scalars (bank-conflict-free)
#define ZLD 132          // ztmp row stride (pad to cut 4-way pickup conflicts)

// LDS: xw 49152 + regB 13824 + wxT 36*129*4=18576 -> 81552 B <= 81920 -> 2 blocks/CU
// VGPR: waves_per_eu(4,4) pins budget at 128 (512-reg pool / 4 waves) -> no spill-squeeze
__global__ __launch_bounds__(512)
__attribute__((amdgpu_waves_per_eu(4, 4)))
void mamba_fused(const float* __restrict__ x,
                 const float* __restrict__ W_in,
                 const float* __restrict__ conv_w,
                 const float* __restrict__ conv_b,
                 const float* __restrict__ W_x,
                 const float* __restrict__ W_dt,
                 const float* __restrict__ b_dt,
                 const float* __restrict__ A_log,
                 const float* __restrict__ D_skip,
                 const float* __restrict__ W_out,
                 float* __restrict__ out)
{
    __shared__ __align__(16) float xw[TT * DI];     // xi -> xc (conv in-place) -> y_final
    __shared__ __align__(16) float regB[3456];      // {xstage[1024] | ztmp[16*ZLD]} then dbl[96*36]
    __shared__ __align__(16) float wxT[36 * WXLD];  // W_x transposed [j][c], stride 129

    float* xstage = regB;          // [16][64]
    float* ztmp   = regB + 1024;   // [16][ZLD]  (1024+2112=3136 <= 3456)
    float* dbl    = regB;          // [96][36]

    const int tid = threadIdx.x;
    const int seq = blockIdx.x;
    const int b = seq / NN;
    const int n = seq - b * NN;
    const size_t trow = (size_t)NN * DM;                 // stride between timesteps
    const size_t gbase = ((size_t)b * TT * NN + n) * DM; // offset of (b, 0, n, 0)

    // ---- stage W_x transposed into LDS (coalesced global reads) ----
    for (int idx = tid; idx < 36 * DI; idx += 512) {
        int c = idx / 36;
        int j = idx - c * 36;
        wxT[j * WXLD + c] = W_x[idx];
    }

    // scan-thread identity (z pickup + scan + post-pass)
    const int d = tid >> 2;   // channel 0..127
    const int q = tid & 3;    // state-quad 0..3
    float z_reg[24];          // z(t=4k+q, d) — compile-time indexed only

    // ---- phase A: xz = x @ W_in, chunked over t (6 x 16 rows) ----
    {
        const int c0 = (tid & 63) * 4;   // output column quad (0..252)
        const int tg = tid >> 6;         // 0..7

        #pragma unroll
        for (int ct = 0; ct < NCH; ++ct) {
            // stage x rows [16ct, 16ct+16): 1024 floats, 2 per thread (coalesced)
            {
                int r0 = tid >> 6, col0 = tid & 63;
                xstage[tid] = x[gbase + (size_t)(ct * CHT + r0) * trow + col0];
                int i1 = tid + 512;
                int r1 = i1 >> 6, col1 = i1 & 63;
                xstage[i1] = x[gbase + (size_t)(ct * CHT + r1) * trow + col1];
            }
            // pick up z from PREVIOUS chunk's ztmp
            if (ct > 0) {
                #pragma unroll
                for (int k = 0; k < 4; ++k)
                    z_reg[(ct - 1) * 4 + k] = ztmp[(q + 4 * k) * ZLD + d];
            }
            __syncthreads();

            float acc[2][4];
            #pragma unroll
            for (int i = 0; i < 2; ++i) { acc[i][0]=0.f; acc[i][1]=0.f; acc[i][2]=0.f; acc[i][3]=0.f; }
            for (int k4 = 0; k4 < DM; k4 += 4) {
                float4 w0 = *(const float4*)&W_in[(k4 + 0) * 2 * DI + c0];
                float4 w1 = *(const float4*)&W_in[(k4 + 1) * 2 * DI + c0];
                float4 w2 = *(const float4*)&W_in[(k4 + 2) * 2 * DI + c0];
                float4 w3 = *(const float4*)&W_in[(k4 + 3) * 2 * DI + c0];
                #pragma unroll
                for (int i = 0; i < 2; ++i) {
                    float4 a = *(const float4*)&xstage[(tg + 8 * i) * DM + k4];
                    acc[i][0] += a.x * w0.x + a.y * w1.x + a.z * w2.x + a.w * w3.x;
                    acc[i][1] += a.x * w0.y + a.y * w1.y + a.z * w2.y + a.w * w3.y;
                    acc[i][2] += a.x * w0.z + a.y * w1.z + a.z * w2.z + a.w * w3.z;
                    acc[i][3] += a.x * w0.w + a.y * w1.w + a.z * w2.w + a.w * w3.w;
                }
            }
            #pragma unroll
            for (int i = 0; i < 2; ++i) {
                int tl = tg + 8 * i;
                float4 v = make_float4(acc[i][0], acc[i][1], acc[i][2], acc[i][3]);
                if (c0 < DI) *(float4*)&xw[(ct * CHT + tl) * DI + c0] = v;
                else         *(float4*)&ztmp[tl * ZLD + (c0 - DI)] = v;
            }
            __syncthreads();
        }
        // final chunk's z pickup
        #pragma unroll
        for (int k = 0; k < 4; ++k)
            z_reg[20 + k] = ztmp[(q + 4 * k) * ZLD + d];
    }

    // ---- causal conv4 + bias + SiLU, in-place on xw, descending 32-t chunks ----
    {
        const int c = tid & 127;
        const int tq = tid >> 7;  // 0..3
        const float4 cw = *(const float4*)&conv_w[c * 4];
        const float cb = conv_b[c];
        for (int chunk = 2; chunk >= 0; --chunk) {
            const int tb = chunk * 32;
            float v[8];
            #pragma unroll
            for (int i = 0; i < 8; ++i) {
                int t = tb + tq + 4 * i;
                float s = cb + xw[t * DI + c] * cw.w;
                if (t - 1 >= 0) s += xw[(t - 1) * DI + c] * cw.z;
                if (t - 2 >= 0) s += xw[(t - 2) * DI + c] * cw.y;
                if (t - 3 >= 0) s += xw[(t - 3) * DI + c] * cw.x;
                v[i] = s / (1.f + __expf(-s));   // silu
            }
            __syncthreads();
            #pragma unroll
            for (int i = 0; i < 8; ++i) {
                int t = tb + tq + 4 * i;
                xw[t * DI + c] = v[i];
            }
            __syncthreads();
        }
    }

    // ---- dbl = xc @ W_x  -> dbl[t*36 + j]  (dt_r | B | C) ----
    // xw read rotated by t (2-way, free); wxT read as 4 scalars, stride 129:
    // bank = (jl + 4*((cc+t)%8) + comp) % 32 -> injective over the wave's (jl,t'') combos.
    {
        const int t = tid >> 2;    // 0..127 (guard <96)
        const int jl = tid & 3;
        if (t < TT) {
            float acc[9];
            #pragma unroll
            for (int i = 0; i < 9; ++i) acc[i] = 0.f;
            for (int cc = 0; cc < 32; ++cc) {
                const int c4 = ((cc + t) & 31) * 4;
                float4 xv = *(const float4*)&xw[t * DI + c4];
                #pragma unroll
                for (int i = 0; i < 9; ++i) {
                    const float* wr = &wxT[(jl + 4 * i) * WXLD + c4];
                    acc[i] += xv.x * wr[0] + xv.y * wr[1] + xv.z * wr[2] + xv.w * wr[3];
                }
            }
            #pragma unroll
            for (int i = 0; i < 9; ++i)
                dbl[t * 36 + jl + 4 * i] = acc[i];
        }
    }
    __syncthreads();

    // ---- sequential scan over t (barrier-free; 4 lanes per channel d) ----
    {
        const int s0 = q * 4;
        const float w0 = W_dt[0 * DI + d], w1 = W_dt[1 * DI + d];
        const float w2 = W_dt[2 * DI + d], w3 = W_dt[3 * DI + d];
        const float bd = b_dt[d];
        const float4 al = *(const float4*)&A_log[d * NSTATE + s0];
        const float A0 = -__expf(al.x), A1 = -__expf(al.y);
        const float A2 = -__expf(al.z), A3 = -__expf(al.w);
        const float dsk = D_skip[d];
        float h0 = 0.f, h1 = 0.f, h2 = 0.f, h3 = 0.f;
        for (int t = 0; t < TT; ++t) {
            const float* db = &dbl[t * 36];
            float4 dtr = *(const float4*)&db[0];
            float4 Bv  = *(const float4*)&db[4 + s0];
            float4 Cv  = *(const float4*)&db[20 + s0];
            float xc = xw[t * DI + d];
            float pre = bd + dtr.x * w0 + dtr.y * w1 + dtr.z * w2 + dtr.w * w3;
            float dt = (pre > 15.f) ? pre : __logf(1.f + __expf(pre));  // softplus
            float dx = dt * xc;
            h0 = __expf(dt * A0) * h0 + dx * Bv.x;
            h1 = __expf(dt * A1) * h1 + dx * Bv.y;
            h2 = __expf(dt * A2) * h2 + dx * Bv.z;
            h3 = __expf(dt * A3) * h3 + dx * Bv.w;
            float y = h0 * Cv.x + h1 * Cv.y + h2 * Cv.z + h3 * Cv.w;
            y += __shfl_xor(y, 1);
            y += __shfl_xor(y, 2);
            if (q == (t & 3)) {
                xw[t * DI + d] = y + xc * dsk;   // y_raw in-place (own column, own wave)
            }
        }
        // post-pass: multiply own entries by silu(z)
        #pragma unroll
        for (int k = 0; k < 24; ++k) {
            int t = 4 * k + q;
            float zz = z_reg[k];
            float sz = zz / (1.f + __expf(-zz));
            xw[t * DI + d] *= sz;
        }
    }
    __syncthreads();

    // ---- phase C: out = y_final @ W_out (cc rotated by 2*tg -> conflict-free xw reads) ----
    {
        const int o0 = (tid & 15) * 4;  // output dim quad
        const int tg = tid >> 4;        // 0..31, t = tg + 32*i
        float acc[3][4];
        #pragma unroll
        for (int i = 0; i < 3; ++i) { acc[i][0]=0.f; acc[i][1]=0.f; acc[i][2]=0.f; acc[i][3]=0.f; }
        for (int cc = 0; cc < 32; ++cc) {
            const int ccp = (cc + 2 * (tg & 3)) & 31;
            float4 w0 = *(const float4*)&W_out[(ccp * 4 + 0) * DM + o0];
            float4 w1 = *(const float4*)&W_out[(ccp * 4 + 1) * DM + o0];
            float4 w2 = *(const float4*)&W_out[(ccp * 4 + 2) * DM + o0];
            float4 w3 = *(const float4*)&W_out[(ccp * 4 + 3) * DM + o0];
            #pragma unroll
            for (int i = 0; i < 3; ++i) {
                float4 y4 = *(const float4*)&xw[(tg + 32 * i) * DI + ccp * 4];
                acc[i][0] += y4.x * w0.x + y4.y * w1.x + y4.z * w2.x + y4.w * w3.x;
                acc[i][1] += y4.x * w0.y + y4.y * w1.y + y4.z * w2.y + y4.w * w3.y;
                acc[i][2] += y4.x * w0.z + y4.y * w1.z + y4.z * w2.z + y4.w * w3.z;
                acc[i][3] += y4.x * w0.w + y4.y * w1.w + y4.z * w2.w + y4.w * w3.w;
            }
        }
        #pragma unroll
        for (int i = 0; i < 3; ++i) {
            int t = tg + 32 * i;
            *(float4*)&out[gbase + (size_t)t * trow + o0] =
                make_float4(acc[i][0], acc[i][1], acc[i][2], acc[i][3]);
        }
    }
}

extern "C" void kernel_launch(void* const* d_in, const int* in_sizes, int n_in,
                              void* d_out, int out_size, void* d_ws, size_t ws_size,
                              hipStream_t stream) {
    const float* x      = (const float*)d_in[0];
    const float* W_in   = (const float*)d_in[1];
    const float* conv_w = (const float*)d_in[2];
    const float* conv_b = (const float*)d_in[3];
    const float* W_x    = (const float*)d_in[4];
    const float* W_dt   = (const float*)d_in[5];
    const float* b_dt   = (const float*)d_in[6];
    const float* A_log  = (const float*)d_in[7];
    const float* D_skip = (const float*)d_in[8];
    const float* W_out  = (const float*)d_in[9];
    float* outp = (float*)d_out;

    dim3 grid(NBATCH * NN);  // 5200 sequences
    mamba_fused<<<grid, 512, 0, stream>>>(x, W_in, conv_w, conv_b, W_x, W_dt,
                                          b_dt, A_log, D_skip, W_out, outp);
}

// Round 5
// 5251.479 us; speedup vs baseline: 1.7087x; 1.7087x over previous
//
#include <hip/hip_runtime.h>

#define TT 96
#define DM 64
#define DI 128
#define NSTATE 16
#define NN 325
#define NBATCH 16
#define CHT 16           // t-chunk size for phase A
#define NCH (TT / CHT)   // 6 chunks
#define WXLD 129         // wxT row stride: +1 pad, read as scalars (bank-conflict-free)
#define ZLD 132          // ztmp row stride (pad to cut 4-way pickup conflicts)

// LDS: xw 49152 + regB 13824 + wxT 36*129*4=18576 -> 81552 B (granule 81920) -> 2 blocks/CU
// VGPR: demand-driven. (512,1) gave 104 in R1 with no spill; stronger occupancy hints
// ((512,4) or amdgpu_waves_per_eu(4,4)) both collapsed the budget to 64 and spilled ~26 GB.
__global__ __launch_bounds__(512, 1)
void mamba_fused(const float* __restrict__ x,
                 const float* __restrict__ W_in,
                 const float* __restrict__ conv_w,
                 const float* __restrict__ conv_b,
                 const float* __restrict__ W_x,
                 const float* __restrict__ W_dt,
                 const float* __restrict__ b_dt,
                 const float* __restrict__ A_log,
                 const float* __restrict__ D_skip,
                 const float* __restrict__ W_out,
                 float* __restrict__ out)
{
    __shared__ __align__(16) float xw[TT * DI];     // xi -> xc (conv in-place) -> y_final
    __shared__ __align__(16) float regB[3456];      // {xstage[1024] | ztmp[16*ZLD]} then dbl[96*36]
    __shared__ __align__(16) float wxT[36 * WXLD];  // W_x transposed [j][c], stride 129

    float* xstage = regB;          // [16][64]
    float* ztmp   = regB + 1024;   // [16][ZLD]  (1024+2112=3136 <= 3456)
    float* dbl    = regB;          // [96][36]

    const int tid = threadIdx.x;
    const int seq = blockIdx.x;
    const int b = seq / NN;
    const int n = seq - b * NN;
    const size_t trow = (size_t)NN * DM;                 // stride between timesteps
    const size_t gbase = ((size_t)b * TT * NN + n) * DM; // offset of (b, 0, n, 0)

    // ---- stage W_x transposed into LDS (coalesced global reads) ----
    for (int idx = tid; idx < 36 * DI; idx += 512) {
        int c = idx / 36;
        int j = idx - c * 36;
        wxT[j * WXLD + c] = W_x[idx];
    }

    // scan-thread identity (z pickup + scan + post-pass)
    const int d = tid >> 2;   // channel 0..127
    const int q = tid & 3;    // state-quad 0..3
    float z_reg[24];          // z(t=4k+q, d) — compile-time indexed only

    // ---- phase A: xz = x @ W_in, chunked over t (6 x 16 rows) ----
    {
        const int c0 = (tid & 63) * 4;   // output column quad (0..252)
        const int tg = tid >> 6;         // 0..7

        #pragma unroll
        for (int ct = 0; ct < NCH; ++ct) {
            // stage x rows [16ct, 16ct+16): 1024 floats, 2 per thread (coalesced)
            {
                int r0 = tid >> 6, col0 = tid & 63;
                xstage[tid] = x[gbase + (size_t)(ct * CHT + r0) * trow + col0];
                int i1 = tid + 512;
                int r1 = i1 >> 6, col1 = i1 & 63;
                xstage[i1] = x[gbase + (size_t)(ct * CHT + r1) * trow + col1];
            }
            // pick up z from PREVIOUS chunk's ztmp
            if (ct > 0) {
                #pragma unroll
                for (int k = 0; k < 4; ++k)
                    z_reg[(ct - 1) * 4 + k] = ztmp[(q + 4 * k) * ZLD + d];
            }
            __syncthreads();

            float acc[2][4];
            #pragma unroll
            for (int i = 0; i < 2; ++i) { acc[i][0]=0.f; acc[i][1]=0.f; acc[i][2]=0.f; acc[i][3]=0.f; }
            for (int k4 = 0; k4 < DM; k4 += 4) {
                float4 w0 = *(const float4*)&W_in[(k4 + 0) * 2 * DI + c0];
                float4 w1 = *(const float4*)&W_in[(k4 + 1) * 2 * DI + c0];
                float4 w2 = *(const float4*)&W_in[(k4 + 2) * 2 * DI + c0];
                float4 w3 = *(const float4*)&W_in[(k4 + 3) * 2 * DI + c0];
                #pragma unroll
                for (int i = 0; i < 2; ++i) {
                    float4 a = *(const float4*)&xstage[(tg + 8 * i) * DM + k4];
                    acc[i][0] += a.x * w0.x + a.y * w1.x + a.z * w2.x + a.w * w3.x;
                    acc[i][1] += a.x * w0.y + a.y * w1.y + a.z * w2.y + a.w * w3.y;
                    acc[i][2] += a.x * w0.z + a.y * w1.z + a.z * w2.z + a.w * w3.z;
                    acc[i][3] += a.x * w0.w + a.y * w1.w + a.z * w2.w + a.w * w3.w;
                }
            }
            #pragma unroll
            for (int i = 0; i < 2; ++i) {
                int tl = tg + 8 * i;
                float4 v = make_float4(acc[i][0], acc[i][1], acc[i][2], acc[i][3]);
                if (c0 < DI) *(float4*)&xw[(ct * CHT + tl) * DI + c0] = v;
                else         *(float4*)&ztmp[tl * ZLD + (c0 - DI)] = v;
            }
            __syncthreads();
        }
        // final chunk's z pickup (ordered before dbl overwrite by conv's barriers)
        #pragma unroll
        for (int k = 0; k < 4; ++k)
            z_reg[20 + k] = ztmp[(q + 4 * k) * ZLD + d];
    }

    // ---- causal conv4 + bias + SiLU, in-place on xw, descending 32-t chunks ----
    {
        const int c = tid & 127;
        const int tq = tid >> 7;  // 0..3
        const float4 cw = *(const float4*)&conv_w[c * 4];
        const float cb = conv_b[c];
        for (int chunk = 2; chunk >= 0; --chunk) {
            const int tb = chunk * 32;
            float v[8];
            #pragma unroll
            for (int i = 0; i < 8; ++i) {
                int t = tb + tq + 4 * i;
                float s = cb + xw[t * DI + c] * cw.w;
                if (t - 1 >= 0) s += xw[(t - 1) * DI + c] * cw.z;
                if (t - 2 >= 0) s += xw[(t - 2) * DI + c] * cw.y;
                if (t - 3 >= 0) s += xw[(t - 3) * DI + c] * cw.x;
                v[i] = s / (1.f + __expf(-s));   // silu
            }
            __syncthreads();
            #pragma unroll
            for (int i = 0; i < 8; ++i) {
                int t = tb + tq + 4 * i;
                xw[t * DI + c] = v[i];
            }
            __syncthreads();
        }
    }

    // ---- dbl = xc @ W_x  -> dbl[t*36 + j]  (dt_r | B | C) ----
    // xw read rotated by t (2-way, free); wxT read as 4 scalars, stride 129:
    // bank = (jl + 4*((cc+t)%8)*... ) -> spread, ~conflict-free.
    {
        const int t = tid >> 2;    // 0..127 (guard <96)
        const int jl = tid & 3;
        if (t < TT) {
            float acc[9];
            #pragma unroll
            for (int i = 0; i < 9; ++i) acc[i] = 0.f;
            for (int cc = 0; cc < 32; ++cc) {
                const int c4 = ((cc + t) & 31) * 4;
                float4 xv = *(const float4*)&xw[t * DI + c4];
                #pragma unroll
                for (int i = 0; i < 9; ++i) {
                    const float* wr = &wxT[(jl + 4 * i) * WXLD + c4];
                    acc[i] += xv.x * wr[0] + xv.y * wr[1] + xv.z * wr[2] + xv.w * wr[3];
                }
            }
            #pragma unroll
            for (int i = 0; i < 9; ++i)
                dbl[t * 36 + jl + 4 * i] = acc[i];
        }
    }
    __syncthreads();

    // ---- sequential scan over t (barrier-free; 4 lanes per channel d) ----
    {
        const int s0 = q * 4;
        const float w0 = W_dt[0 * DI + d], w1 = W_dt[1 * DI + d];
        const float w2 = W_dt[2 * DI + d], w3 = W_dt[3 * DI + d];
        const float bd = b_dt[d];
        const float4 al = *(const float4*)&A_log[d * NSTATE + s0];
        const float A0 = -__expf(al.x), A1 = -__expf(al.y);
        const float A2 = -__expf(al.z), A3 = -__expf(al.w);
        const float dsk = D_skip[d];
        float h0 = 0.f, h1 = 0.f, h2 = 0.f, h3 = 0.f;
        for (int t = 0; t < TT; ++t) {
            const float* db = &dbl[t * 36];
            float4 dtr = *(const float4*)&db[0];
            float4 Bv  = *(const float4*)&db[4 + s0];
            float4 Cv  = *(const float4*)&db[20 + s0];
            float xc = xw[t * DI + d];
            float pre = bd + dtr.x * w0 + dtr.y * w1 + dtr.z * w2 + dtr.w * w3;
            float dt = (pre > 15.f) ? pre : __logf(1.f + __expf(pre));  // softplus
            float dx = dt * xc;
            h0 = __expf(dt * A0) * h0 + dx * Bv.x;
            h1 = __expf(dt * A1) * h1 + dx * Bv.y;
            h2 = __expf(dt * A2) * h2 + dx * Bv.z;
            h3 = __expf(dt * A3) * h3 + dx * Bv.w;
            float y = h0 * Cv.x + h1 * Cv.y + h2 * Cv.z + h3 * Cv.w;
            y += __shfl_xor(y, 1);
            y += __shfl_xor(y, 2);
            if (q == (t & 3)) {
                xw[t * DI + d] = y + xc * dsk;   // y_raw in-place (own column, own wave)
            }
        }
        // post-pass: multiply own entries by silu(z)
        #pragma unroll
        for (int k = 0; k < 24; ++k) {
            int t = 4 * k + q;
            float zz = z_reg[k];
            float sz = zz / (1.f + __expf(-zz));
            xw[t * DI + d] *= sz;
        }
    }
    __syncthreads();

    // ---- phase C: out = y_final @ W_out (cc rotated by 2*tg -> conflict-free xw reads) ----
    {
        const int o0 = (tid & 15) * 4;  // output dim quad
        const int tg = tid >> 4;        // 0..31, t = tg + 32*i
        float acc[3][4];
        #pragma unroll
        for (int i = 0; i < 3; ++i) { acc[i][0]=0.f; acc[i][1]=0.f; acc[i][2]=0.f; acc[i][3]=0.f; }
        for (int cc = 0; cc < 32; ++cc) {
            const int ccp = (cc + 2 * (tg & 3)) & 31;
            float4 w0 = *(const float4*)&W_out[(ccp * 4 + 0) * DM + o0];
            float4 w1 = *(const float4*)&W_out[(ccp * 4 + 1) * DM + o0];
            float4 w2 = *(const float4*)&W_out[(ccp * 4 + 2) * DM + o0];
            float4 w3 = *(const float4*)&W_out[(ccp * 4 + 3) * DM + o0];
            #pragma unroll
            for (int i = 0; i < 3; ++i) {
                float4 y4 = *(const float4*)&xw[(tg + 32 * i) * DI + ccp * 4];
                acc[i][0] += y4.x * w0.x + y4.y * w1.x + y4.z * w2.x + y4.w * w3.x;
                acc[i][1] += y4.x * w0.y + y4.y * w1.y + y4.z * w2.y + y4.w * w3.y;
                acc[i][2] += y4.x * w0.z + y4.y * w1.z + y4.z * w2.z + y4.w * w3.z;
                acc[i][3] += y4.x * w0.w + y4.y * w1.w + y4.z * w2.w + y4.w * w3.w;
            }
        }
        #pragma unroll
        for (int i = 0; i < 3; ++i) {
            int t = tg + 32 * i;
            *(float4*)&out[gbase + (size_t)t * trow + o0] =
                make_float4(acc[i][0], acc[i][1], acc[i][2], acc[i][3]);
        }
    }
}

extern "C" void kernel_launch(void* const* d_in, const int* in_sizes, int n_in,
                              void* d_out, int out_size, void* d_ws, size_t ws_size,
                              hipStream_t stream) {
    const float* x      = (const float*)d_in[0];
    const float* W_in   = (const float*)d_in[1];
    const float* conv_w = (const float*)d_in[2];
    const float* conv_b = (const float*)d_in[3];
    const float* W_x    = (const float*)d_in[4];
    const float* W_dt   = (const float*)d_in[5];
    const float* b_dt   = (const float*)d_in[6];
    const float* A_log  = (const float*)d_in[7];
    const float* D_skip = (const float*)d_in[8];
    const float* W_out  = (const float*)d_in[9];
    float* outp = (float*)d_out;

    dim3 grid(NBATCH * NN);  // 5200 sequences
    mamba_fused<<<grid, 512, 0, stream>>>(x, W_in, conv_w, conv_b, W_x, W_dt,
                                          b_dt, A_log, D_skip, W_out, outp);
}

// Round 7
// 3394.651 us; speedup vs baseline: 2.6433x; 1.5470x over previous
//
#include <hip/hip_runtime.h>

#define TT 96
#define DM 64
#define DI 128
#define NSTATE 16
#define NN 325
#define NBATCH 16
#define CHT 16           // t-chunk size for phase A / Z
#define NCH (TT / CHT)   // 6 chunks
#define WXLD 129         // wxT row stride: +1 pad, scalar reads (bank-conflict-free)

// LDS: xw 49152 + regB 13824 + wxT 18576 = 81552 B -> 2 blocks/CU (proven R3)
// VGPR: demand-driven (512,1). No z_reg, no ztmp -> demand ~100, no spill.
__global__ __launch_bounds__(512, 1)
void mamba_fused(const float* __restrict__ x,
                 const float* __restrict__ W_in,
                 const float* __restrict__ conv_w,
                 const float* __restrict__ conv_b,
                 const float* __restrict__ W_x,
                 const float* __restrict__ W_dt,
                 const float* __restrict__ b_dt,
                 const float* __restrict__ A_log,
                 const float* __restrict__ D_skip,
                 const float* __restrict__ W_out,
                 float* __restrict__ out)
{
    __shared__ __align__(16) float xw[TT * DI];     // xi -> xc (conv in-place) -> y_raw -> y_final
    __shared__ __align__(16) float regB[3456];      // xstage[1024] | dbl[96*36] (time-shared)
    __shared__ __align__(16) float wxT[36 * WXLD];  // W_x transposed [j][c], stride 129

    float* xstage = regB;          // [16][64]
    float* dbl    = regB;          // [96][36]

    const int tid = threadIdx.x;
    const int seq = blockIdx.x;
    const int b = seq / NN;
    const int n = seq - b * NN;
    const size_t trow = (size_t)NN * DM;                 // stride between timesteps
    const size_t gbase = ((size_t)b * TT * NN + n) * DM; // offset of (b, 0, n, 0)

    // ---- stage W_x transposed into LDS (coalesced global reads) ----
    for (int idx = tid; idx < 36 * DI; idx += 512) {
        int c = idx / 36;
        int j = idx - c * 36;
        wxT[j * WXLD + c] = W_x[idx];
    }

    // ---- phase A: xi = x @ W_in[:, 0:128], chunked over t (6 x 16 rows) ----
    {
        const int r  = tid >> 5;         // 0..15 row within chunk
        const int c0 = (tid & 31) * 4;   // output col quad 0..124
        for (int ct = 0; ct < NCH; ++ct) {
            {   // stage x rows [16ct, 16ct+16): 1024 floats, 2 per thread (coalesced)
                int i0 = tid;
                xstage[i0] = x[gbase + (size_t)(ct * CHT + (i0 >> 6)) * trow + (i0 & 63)];
                int i1 = tid + 512;
                xstage[i1] = x[gbase + (size_t)(ct * CHT + (i1 >> 6)) * trow + (i1 & 63)];
            }
            __syncthreads();
            float a0 = 0.f, a1 = 0.f, a2 = 0.f, a3 = 0.f;
            for (int k4 = 0; k4 < DM; k4 += 4) {
                float4 a  = *(const float4*)&xstage[r * DM + k4];
                float4 w0 = *(const float4*)&W_in[(k4 + 0) * 2 * DI + c0];
                float4 w1 = *(const float4*)&W_in[(k4 + 1) * 2 * DI + c0];
                float4 w2 = *(const float4*)&W_in[(k4 + 2) * 2 * DI + c0];
                float4 w3 = *(const float4*)&W_in[(k4 + 3) * 2 * DI + c0];
                a0 += a.x * w0.x + a.y * w1.x + a.z * w2.x + a.w * w3.x;
                a1 += a.x * w0.y + a.y * w1.y + a.z * w2.y + a.w * w3.y;
                a2 += a.x * w0.z + a.y * w1.z + a.z * w2.z + a.w * w3.z;
                a3 += a.x * w0.w + a.y * w1.w + a.z * w2.w + a.w * w3.w;
            }
            *(float4*)&xw[(ct * CHT + r) * DI + c0] = make_float4(a0, a1, a2, a3);
            __syncthreads();   // xstage reused next chunk
        }
    }

    // ---- causal conv4 + bias + SiLU, in-place on xw, descending 32-t chunks ----
    {
        const int c = tid & 127;
        const int tq = tid >> 7;  // 0..3
        const float4 cw = *(const float4*)&conv_w[c * 4];
        const float cb = conv_b[c];
        for (int chunk = 2; chunk >= 0; --chunk) {
            const int tb = chunk * 32;
            float v[8];
            #pragma unroll
            for (int i = 0; i < 8; ++i) {
                int t = tb + tq + 4 * i;
                float s = cb + xw[t * DI + c] * cw.w;
                if (t - 1 >= 0) s += xw[(t - 1) * DI + c] * cw.z;
                if (t - 2 >= 0) s += xw[(t - 2) * DI + c] * cw.y;
                if (t - 3 >= 0) s += xw[(t - 3) * DI + c] * cw.x;
                v[i] = s / (1.f + __expf(-s));   // silu
            }
            __syncthreads();
            #pragma unroll
            for (int i = 0; i < 8; ++i) {
                int t = tb + tq + 4 * i;
                xw[t * DI + c] = v[i];
            }
            __syncthreads();
        }
    }

    // ---- dbl = xc @ W_x  -> dbl[t*36 + j]  (dt_r | B | C) ----
    {
        const int t = tid >> 2;    // 0..127 (guard <96)
        const int jl = tid & 3;
        if (t < TT) {
            float acc[9];
            #pragma unroll
            for (int i = 0; i < 9; ++i) acc[i] = 0.f;
            for (int cc = 0; cc < 32; ++cc) {
                const int c4 = ((cc + t) & 31) * 4;   // rotate to spread banks (2-way, free)
                float4 xv = *(const float4*)&xw[t * DI + c4];
                #pragma unroll
                for (int i = 0; i < 9; ++i) {
                    const float* wr = &wxT[(jl + 4 * i) * WXLD + c4];
                    acc[i] += xv.x * wr[0] + xv.y * wr[1] + xv.z * wr[2] + xv.w * wr[3];
                }
            }
            #pragma unroll
            for (int i = 0; i < 9; ++i)
                dbl[t * 36 + jl + 4 * i] = acc[i];
        }
    }
    __syncthreads();

    // ---- sequential scan over t (barrier-free; 4 lanes per channel d) ----
    {
        const int d = tid >> 2;   // channel 0..127
        const int q = tid & 3;    // state-quad 0..3
        const int s0 = q * 4;
        const float w0 = W_dt[0 * DI + d], w1 = W_dt[1 * DI + d];
        const float w2 = W_dt[2 * DI + d], w3 = W_dt[3 * DI + d];
        const float bd = b_dt[d];
        const float4 al = *(const float4*)&A_log[d * NSTATE + s0];
        const float A0 = -__expf(al.x), A1 = -__expf(al.y);
        const float A2 = -__expf(al.z), A3 = -__expf(al.w);
        const float dsk = D_skip[d];
        float h0 = 0.f, h1 = 0.f, h2 = 0.f, h3 = 0.f;
        for (int t = 0; t < TT; ++t) {
            const float* db = &dbl[t * 36];
            float4 dtr = *(const float4*)&db[0];
            float4 Bv  = *(const float4*)&db[4 + s0];
            float4 Cv  = *(const float4*)&db[20 + s0];
            float xc = xw[t * DI + d];
            float pre = bd + dtr.x * w0 + dtr.y * w1 + dtr.z * w2 + dtr.w * w3;
            float dt = (pre > 15.f) ? pre : __logf(1.f + __expf(pre));  // softplus
            float dx = dt * xc;
            h0 = __expf(dt * A0) * h0 + dx * Bv.x;
            h1 = __expf(dt * A1) * h1 + dx * Bv.y;
            h2 = __expf(dt * A2) * h2 + dx * Bv.z;
            h3 = __expf(dt * A3) * h3 + dx * Bv.w;
            float y = h0 * Cv.x + h1 * Cv.y + h2 * Cv.z + h3 * Cv.w;
            y += __shfl_xor(y, 1);
            y += __shfl_xor(y, 2);
            if (q == (t & 3)) {
                xw[t * DI + d] = y + xc * dsk;   // y_raw in-place (own column, own wave)
            }
        }
    }
    __syncthreads();   // scan done: dbl dead, xw holds y_raw

    // ---- phase Z: recompute z = x @ W_in[:, 128:256]; xw *= silu(z), chunked ----
    {
        const int r  = tid >> 5;         // 0..15 row within chunk
        const int c0 = (tid & 31) * 4;   // z col quad 0..124
        for (int ct = 0; ct < NCH; ++ct) {
            {   // re-stage x rows (dbl region is dead)
                int i0 = tid;
                xstage[i0] = x[gbase + (size_t)(ct * CHT + (i0 >> 6)) * trow + (i0 & 63)];
                int i1 = tid + 512;
                xstage[i1] = x[gbase + (size_t)(ct * CHT + (i1 >> 6)) * trow + (i1 & 63)];
            }
            __syncthreads();
            float a0 = 0.f, a1 = 0.f, a2 = 0.f, a3 = 0.f;
            for (int k4 = 0; k4 < DM; k4 += 4) {
                float4 a  = *(const float4*)&xstage[r * DM + k4];
                float4 w0 = *(const float4*)&W_in[(k4 + 0) * 2 * DI + DI + c0];
                float4 w1 = *(const float4*)&W_in[(k4 + 1) * 2 * DI + DI + c0];
                float4 w2 = *(const float4*)&W_in[(k4 + 2) * 2 * DI + DI + c0];
                float4 w3 = *(const float4*)&W_in[(k4 + 3) * 2 * DI + DI + c0];
                a0 += a.x * w0.x + a.y * w1.x + a.z * w2.x + a.w * w3.x;
                a1 += a.x * w0.y + a.y * w1.y + a.z * w2.y + a.w * w3.y;
                a2 += a.x * w0.z + a.y * w1.z + a.z * w2.z + a.w * w3.z;
                a3 += a.x * w0.w + a.y * w1.w + a.z * w2.w + a.w * w3.w;
            }
            const int rg = ct * CHT + r;
            float4 y4 = *(const float4*)&xw[rg * DI + c0];
            y4.x *= a0 / (1.f + __expf(-a0));
            y4.y *= a1 / (1.f + __expf(-a1));
            y4.z *= a2 / (1.f + __expf(-a2));
            y4.w *= a3 / (1.f + __expf(-a3));
            *(float4*)&xw[rg * DI + c0] = y4;
            __syncthreads();
        }
    }

    // ---- phase C: out = y_final @ W_out (cc rotated by 2*tg -> conflict-free xw reads) ----
    {
        const int o0 = (tid & 15) * 4;  // output dim quad
        const int tg = tid >> 4;        // 0..31, t = tg + 32*i
        float acc[3][4];
        #pragma unroll
        for (int i = 0; i < 3; ++i) { acc[i][0]=0.f; acc[i][1]=0.f; acc[i][2]=0.f; acc[i][3]=0.f; }
        for (int cc = 0; cc < 32; ++cc) {
            const int ccp = (cc + 2 * (tg & 3)) & 31;
            float4 w0 = *(const float4*)&W_out[(ccp * 4 + 0) * DM + o0];
            float4 w1 = *(const float4*)&W_out[(ccp * 4 + 1) * DM + o0];
            float4 w2 = *(const float4*)&W_out[(ccp * 4 + 2) * DM + o0];
            float4 w3 = *(const float4*)&W_out[(ccp * 4 + 3) * DM + o0];
            #pragma unroll
            for (int i = 0; i < 3; ++i) {
                float4 y4 = *(const float4*)&xw[(tg + 32 * i) * DI + ccp * 4];
                acc[i][0] += y4.x * w0.x + y4.y * w1.x + y4.z * w2.x + y4.w * w3.x;
                acc[i][1] += y4.x * w0.y + y4.y * w1.y + y4.z * w2.y + y4.w * w3.y;
                acc[i][2] += y4.x * w0.z + y4.y * w1.z + y4.z * w2.z + y4.w * w3.z;
                acc[i][3] += y4.x * w0.w + y4.y * w1.w + y4.z * w2.w + y4.w * w3.w;
            }
        }
        #pragma unroll
        for (int i = 0; i < 3; ++i) {
            int t = tg + 32 * i;
            *(float4*)&out[gbase + (size_t)t * trow + o0] =
                make_float4(acc[i][0], acc[i][1], acc[i][2], acc[i][3]);
        }
    }
}

extern "C" void kernel_launch(void* const* d_in, const int* in_sizes, int n_in,
                              void* d_out, int out_size, void* d_ws, size_t ws_size,
                              hipStream_t stream) {
    const float* x      = (const float*)d_in[0];
    const float* W_in   = (const float*)d_in[1];
    const float* conv_w = (const float*)d_in[2];
    const float* conv_b = (const float*)d_in[3];
    const float* W_x    = (const float*)d_in[4];
    const float* W_dt   = (const float*)d_in[5];
    const float* b_dt   = (const float*)d_in[6];
    const float* A_log  = (const float*)d_in[7];
    const float* D_skip = (const float*)d_in[8];
    const float* W_out  = (const float*)d_in[9];
    float* outp = (float*)d_out;

    dim3 grid(NBATCH * NN);  // 5200 sequences
    mamba_fused<<<grid, 512, 0, stream>>>(x, W_in, conv_w, conv_b, W_x, W_dt,
                                          b_dt, A_log, D_skip, W_out, outp);
}

// Round 8
// 1559.589 us; speedup vs baseline: 5.7535x; 2.1766x over previous
//
#include <hip/hip_runtime.h>

#define TT 96
#define DM 64
#define DI 128
#define NSTATE 16
#define NN 325
#define NBATCH 16
#define CHT 16           // t-chunk size for phase A / Z
#define NCH (TT / CHT)   // 6 chunks
#define WXLD 129         // wxT row stride: +1 pad, scalar reads (bank-conflict-free)

#define PHASE_FENCE() __builtin_amdgcn_sched_barrier(0)

// LDS: xw 49152 + regB 13824 + wxT 18576 = 81552 B -> 2 blocks/CU (proven R3)
// VGPR: demand-driven (512,1). Partial unrolls + phase fences bound load hoisting.
__global__ __launch_bounds__(512, 1)
void mamba_fused(const float* __restrict__ x,
                 const float* __restrict__ W_in,
                 const float* __restrict__ conv_w,
                 const float* __restrict__ conv_b,
                 const float* __restrict__ W_x,
                 const float* __restrict__ W_dt,
                 const float* __restrict__ b_dt,
                 const float* __restrict__ A_log,
                 const float* __restrict__ D_skip,
                 const float* __restrict__ W_out,
                 float* __restrict__ out)
{
    __shared__ __align__(16) float xw[TT * DI];     // xi -> xc (conv in-place) -> y_raw -> y_final
    __shared__ __align__(16) float regB[3456];      // xstage[1024] | dbl[96*36] (time-shared)
    __shared__ __align__(16) float wxT[36 * WXLD];  // W_x transposed [j][c], stride 129

    float* xstage = regB;          // [16][64]
    float* dbl    = regB;          // [96][36]

    const int tid = threadIdx.x;
    const int seq = blockIdx.x;
    const int b = seq / NN;
    const int n = seq - b * NN;
    const size_t trow = (size_t)NN * DM;                 // stride between timesteps
    const size_t gbase = ((size_t)b * TT * NN + n) * DM; // offset of (b, 0, n, 0)

    // ---- stage W_x transposed into LDS (coalesced global reads) ----
    for (int idx = tid; idx < 36 * DI; idx += 512) {
        int c = idx / 36;
        int j = idx - c * 36;
        wxT[j * WXLD + c] = W_x[idx];
    }

    // ---- phase A: xi = x @ W_in[:, 0:128], chunked over t (6 x 16 rows) ----
    {
        const int r  = tid >> 5;         // 0..15 row within chunk
        const int c0 = (tid & 31) * 4;   // output col quad 0..124
        for (int ct = 0; ct < NCH; ++ct) {
            {   // stage x rows [16ct, 16ct+16): 1024 floats, 2 per thread (coalesced)
                int i0 = tid;
                xstage[i0] = x[gbase + (size_t)(ct * CHT + (i0 >> 6)) * trow + (i0 & 63)];
                int i1 = tid + 512;
                xstage[i1] = x[gbase + (size_t)(ct * CHT + (i1 >> 6)) * trow + (i1 & 63)];
            }
            __syncthreads();
            float a0 = 0.f, a1 = 0.f, a2 = 0.f, a3 = 0.f;
            #pragma unroll 4
            for (int k4 = 0; k4 < DM; k4 += 4) {
                float4 a  = *(const float4*)&xstage[r * DM + k4];
                float4 w0 = *(const float4*)&W_in[(k4 + 0) * 2 * DI + c0];
                float4 w1 = *(const float4*)&W_in[(k4 + 1) * 2 * DI + c0];
                float4 w2 = *(const float4*)&W_in[(k4 + 2) * 2 * DI + c0];
                float4 w3 = *(const float4*)&W_in[(k4 + 3) * 2 * DI + c0];
                a0 += a.x * w0.x + a.y * w1.x + a.z * w2.x + a.w * w3.x;
                a1 += a.x * w0.y + a.y * w1.y + a.z * w2.y + a.w * w3.y;
                a2 += a.x * w0.z + a.y * w1.z + a.z * w2.z + a.w * w3.z;
                a3 += a.x * w0.w + a.y * w1.w + a.z * w2.w + a.w * w3.w;
            }
            *(float4*)&xw[(ct * CHT + r) * DI + c0] = make_float4(a0, a1, a2, a3);
            __syncthreads();   // xstage reused next chunk
        }
    }
    PHASE_FENCE();

    // ---- causal conv4 + bias + SiLU, in-place on xw, descending 32-t chunks ----
    {
        const int c = tid & 127;
        const int tq = tid >> 7;  // 0..3
        const float4 cw = *(const float4*)&conv_w[c * 4];
        const float cb = conv_b[c];
        for (int chunk = 2; chunk >= 0; --chunk) {
            const int tb = chunk * 32;
            float v[8];
            #pragma unroll
            for (int i = 0; i < 8; ++i) {
                int t = tb + tq + 4 * i;
                float s = cb + xw[t * DI + c] * cw.w;
                if (t - 1 >= 0) s += xw[(t - 1) * DI + c] * cw.z;
                if (t - 2 >= 0) s += xw[(t - 2) * DI + c] * cw.y;
                if (t - 3 >= 0) s += xw[(t - 3) * DI + c] * cw.x;
                v[i] = s / (1.f + __expf(-s));   // silu
            }
            __syncthreads();
            #pragma unroll
            for (int i = 0; i < 8; ++i) {
                int t = tb + tq + 4 * i;
                xw[t * DI + c] = v[i];
            }
            __syncthreads();
        }
    }
    PHASE_FENCE();

    // ---- dbl = xc @ W_x  -> dbl[t*36 + j]  (dt_r | B | C) ----
    {
        const int t = tid >> 2;    // 0..127 (guard <96)
        const int jl = tid & 3;
        if (t < TT) {
            float acc[9];
            #pragma unroll
            for (int i = 0; i < 9; ++i) acc[i] = 0.f;
            #pragma unroll 2
            for (int cc = 0; cc < 32; ++cc) {
                const int c4 = ((cc + t) & 31) * 4;   // rotate to spread banks (2-way, free)
                float4 xv = *(const float4*)&xw[t * DI + c4];
                #pragma unroll
                for (int i = 0; i < 9; ++i) {
                    const float* wr = &wxT[(jl + 4 * i) * WXLD + c4];
                    acc[i] += xv.x * wr[0] + xv.y * wr[1] + xv.z * wr[2] + xv.w * wr[3];
                }
            }
            #pragma unroll
            for (int i = 0; i < 9; ++i)
                dbl[t * 36 + jl + 4 * i] = acc[i];
        }
    }
    __syncthreads();
    PHASE_FENCE();

    // ---- sequential scan over t (barrier-free; 4 lanes per channel d) ----
    {
        const int d = tid >> 2;   // channel 0..127
        const int q = tid & 3;    // state-quad 0..3
        const int s0 = q * 4;
        const float w0 = W_dt[0 * DI + d], w1 = W_dt[1 * DI + d];
        const float w2 = W_dt[2 * DI + d], w3 = W_dt[3 * DI + d];
        const float bd = b_dt[d];
        const float4 al = *(const float4*)&A_log[d * NSTATE + s0];
        const float A0 = -__expf(al.x), A1 = -__expf(al.y);
        const float A2 = -__expf(al.z), A3 = -__expf(al.w);
        const float dsk = D_skip[d];
        float h0 = 0.f, h1 = 0.f, h2 = 0.f, h3 = 0.f;
        for (int t = 0; t < TT; ++t) {
            const float* db = &dbl[t * 36];
            float4 dtr = *(const float4*)&db[0];
            float4 Bv  = *(const float4*)&db[4 + s0];
            float4 Cv  = *(const float4*)&db[20 + s0];
            float xc = xw[t * DI + d];
            float pre = bd + dtr.x * w0 + dtr.y * w1 + dtr.z * w2 + dtr.w * w3;
            float dt = (pre > 15.f) ? pre : __logf(1.f + __expf(pre));  // softplus
            float dx = dt * xc;
            h0 = __expf(dt * A0) * h0 + dx * Bv.x;
            h1 = __expf(dt * A1) * h1 + dx * Bv.y;
            h2 = __expf(dt * A2) * h2 + dx * Bv.z;
            h3 = __expf(dt * A3) * h3 + dx * Bv.w;
            float y = h0 * Cv.x + h1 * Cv.y + h2 * Cv.z + h3 * Cv.w;
            y += __shfl_xor(y, 1);
            y += __shfl_xor(y, 2);
            if (q == (t & 3)) {
                xw[t * DI + d] = y + xc * dsk;   // y_raw in-place (own column, own wave)
            }
        }
    }
    __syncthreads();   // scan done: dbl dead, xw holds y_raw
    PHASE_FENCE();

    // ---- phase Z: recompute z = x @ W_in[:, 128:256]; xw *= silu(z), chunked ----
    {
        const int r  = tid >> 5;         // 0..15 row within chunk
        const int c0 = (tid & 31) * 4;   // z col quad 0..124
        for (int ct = 0; ct < NCH; ++ct) {
            {   // re-stage x rows (dbl region is dead)
                int i0 = tid;
                xstage[i0] = x[gbase + (size_t)(ct * CHT + (i0 >> 6)) * trow + (i0 & 63)];
                int i1 = tid + 512;
                xstage[i1] = x[gbase + (size_t)(ct * CHT + (i1 >> 6)) * trow + (i1 & 63)];
            }
            __syncthreads();
            float a0 = 0.f, a1 = 0.f, a2 = 0.f, a3 = 0.f;
            #pragma unroll 4
            for (int k4 = 0; k4 < DM; k4 += 4) {
                float4 a  = *(const float4*)&xstage[r * DM + k4];
                float4 w0 = *(const float4*)&W_in[(k4 + 0) * 2 * DI + DI + c0];
                float4 w1 = *(const float4*)&W_in[(k4 + 1) * 2 * DI + DI + c0];
                float4 w2 = *(const float4*)&W_in[(k4 + 2) * 2 * DI + DI + c0];
                float4 w3 = *(const float4*)&W_in[(k4 + 3) * 2 * DI + DI + c0];
                a0 += a.x * w0.x + a.y * w1.x + a.z * w2.x + a.w * w3.x;
                a1 += a.x * w0.y + a.y * w1.y + a.z * w2.y + a.w * w3.y;
                a2 += a.x * w0.z + a.y * w1.z + a.z * w2.z + a.w * w3.z;
                a3 += a.x * w0.w + a.y * w1.w + a.z * w2.w + a.w * w3.w;
            }
            const int rg = ct * CHT + r;
            float4 y4 = *(const float4*)&xw[rg * DI + c0];
            y4.x *= a0 / (1.f + __expf(-a0));
            y4.y *= a1 / (1.f + __expf(-a1));
            y4.z *= a2 / (1.f + __expf(-a2));
            y4.w *= a3 / (1.f + __expf(-a3));
            *(float4*)&xw[rg * DI + c0] = y4;
            __syncthreads();
        }
    }
    PHASE_FENCE();

    // ---- phase C: out = y_final @ W_out (cc rotated by 2*tg -> conflict-free xw reads) ----
    {
        const int o0 = (tid & 15) * 4;  // output dim quad
        const int tg = tid >> 4;        // 0..31, t = tg + 32*i
        float acc[3][4];
        #pragma unroll
        for (int i = 0; i < 3; ++i) { acc[i][0]=0.f; acc[i][1]=0.f; acc[i][2]=0.f; acc[i][3]=0.f; }
        #pragma unroll 2
        for (int cc = 0; cc < 32; ++cc) {
            const int ccp = (cc + 2 * (tg & 3)) & 31;
            float4 w0 = *(const float4*)&W_out[(ccp * 4 + 0) * DM + o0];
            float4 w1 = *(const float4*)&W_out[(ccp * 4 + 1) * DM + o0];
            float4 w2 = *(const float4*)&W_out[(ccp * 4 + 2) * DM + o0];
            float4 w3 = *(const float4*)&W_out[(ccp * 4 + 3) * DM + o0];
            #pragma unroll
            for (int i = 0; i < 3; ++i) {
                float4 y4 = *(const float4*)&xw[(tg + 32 * i) * DI + ccp * 4];
                acc[i][0] += y4.x * w0.x + y4.y * w1.x + y4.z * w2.x + y4.w * w3.x;
                acc[i][1] += y4.x * w0.y + y4.y * w1.y + y4.z * w2.y + y4.w * w3.y;
                acc[i][2] += y4.x * w0.z + y4.y * w1.z + y4.z * w2.z + y4.w * w3.z;
                acc[i][3] += y4.x * w0.w + y4.y * w1.w + y4.z * w2.w + y4.w * w3.w;
            }
        }
        #pragma unroll
        for (int i = 0; i < 3; ++i) {
            int t = tg + 32 * i;
            *(float4*)&out[gbase + (size_t)t * trow + o0] =
                make_float4(acc[i][0], acc[i][1], acc[i][2], acc[i][3]);
        }
    }
}

extern "C" void kernel_launch(void* const* d_in, const int* in_sizes, int n_in,
                              void* d_out, int out_size, void* d_ws, size_t ws_size,
                              hipStream_t stream) {
    const float* x      = (const float*)d_in[0];
    const float* W_in   = (const float*)d_in[1];
    const float* conv_w = (const float*)d_in[2];
    const float* conv_b = (const float*)d_in[3];
    const float* W_x    = (const float*)d_in[4];
    const float* W_dt   = (const float*)d_in[5];
    const float* b_dt   = (const float*)d_in[6];
    const float* A_log  = (const float*)d_in[7];
    const float* D_skip = (const float*)d_in[8];
    const float* W_out  = (const float*)d_in[9];
    float* outp = (float*)d_out;

    dim3 grid(NBATCH * NN);  // 5200 sequences
    mamba_fused<<<grid, 512, 0, stream>>>(x, W_in, conv_w, conv_b, W_x, W_dt,
                                          b_dt, A_log, D_skip, W_out, outp);
}